// Round 10
// baseline (419.686 us; speedup 1.0000x reference)
//
#include <hip/hip_runtime.h>

#define NUM_E 8
#define N_TOK 8192
#define DIM 1024

typedef __attribute__((ext_vector_type(8))) short short8;
typedef __attribute__((ext_vector_type(4))) float f32x4;

// fp32 -> bf16 round-to-nearest-even
__device__ __forceinline__ unsigned short f2bf(float f) {
  unsigned int u = __float_as_uint(f);
  u = (u + 0x7fffu + ((u >> 16) & 1u)) >> 16;
  return (unsigned short)u;
}

// async global->LDS, 16B per lane. Global addr is per-lane; LDS dest is
// wave-uniform base + lane*16 (m104/m108 semantics).
__device__ __forceinline__ void async16(const unsigned short* g, unsigned short* l) {
  __builtin_amdgcn_global_load_lds((const __attribute__((address_space(1))) void*)g,
                                   (__attribute__((address_space(3))) void*)l,
                                   16, 0, 0);
}

// 64x64 W-transpose tile body (proven since R0): src fp32 [k][n] -> dst bf16 [n][k]
__device__ __forceinline__ void wtile_transpose(const float* src, unsigned short* dst,
                                                int tk, int tn, float (*s)[65]) {
  const int k0 = tk * 64, n0 = tn * 64;
  const int t = threadIdx.x;
  {
    const int rr = t >> 4;
    const int c4 = (t & 15) * 4;
#pragma unroll
    for (int i = 0; i < 4; ++i) {
      const int k = i * 16 + rr;
      float4 v = *(const float4*)&src[(size_t)(k0 + k) * DIM + n0 + c4];
      s[c4 + 0][k] = v.x; s[c4 + 1][k] = v.y;
      s[c4 + 2][k] = v.z; s[c4 + 3][k] = v.w;
    }
  }
  __syncthreads();
  {
    const int kq = (t & 7) * 8;
    const int nn = t >> 3;
#pragma unroll
    for (int r = 0; r < 2; ++r) {
      const int n = r * 32 + nn;
      union { unsigned short us[8]; uint4 v; } o;
#pragma unroll
      for (int j = 0; j < 8; ++j) o.us[j] = f2bf(s[n][kq + j]);
      *(uint4*)(dst + (size_t)(n0 + n) * DIM + k0 + kq) = o.v;
    }
  }
}

// ---------------- L1: gate + x->bf16 + zero(out) + W1 transpose ----------------
// 4096 blocks: even -> gate block (bid>>1); odd -> W1T tile (bid>>1).
// Two memory-bound phases overlap; removes one launch gap.
__global__ __launch_bounds__(256) void prep_gate_w1_kernel(
    const float* __restrict__ x, const float* __restrict__ Wg,
    const float* __restrict__ bg, int* __restrict__ tok_top,
    float2* __restrict__ tok_wts, unsigned short* __restrict__ xb,
    float* __restrict__ out,
    const float* __restrict__ W1, unsigned short* __restrict__ W1T) {
  __shared__ float s[64][65];
  const int bid = blockIdx.x;
  if (bid & 1) {
    const int wv = bid >> 1;             // 0..2047: 8 mats * 16 * 16
    wtile_transpose(W1 + (size_t)(wv >> 8) * (DIM * DIM),
                    W1T + (size_t)(wv >> 8) * (DIM * DIM),
                    (wv >> 4) & 15, wv & 15, s);
    return;
  }
  const int gb = bid >> 1;               // 0..2047
  // zero out: 16KB slice per gate block
  {
    float4* oz = (float4*)(out + (size_t)gb * 4096);
    const float4 z4 = {0.f, 0.f, 0.f, 0.f};
#pragma unroll
    for (int i = 0; i < 4; ++i) oz[i * 256 + threadIdx.x] = z4;
  }
  const int wave = threadIdx.x >> 6;
  const int lane = threadIdx.x & 63;
  const int n = gb * 4 + wave;
  const float4* xr = (const float4*)(x + (size_t)n * DIM);
  unsigned short* xbr = xb + (size_t)n * DIM;
  float acc[NUM_E];
#pragma unroll
  for (int e = 0; e < NUM_E; ++e) acc[e] = 0.f;
#pragma unroll
  for (int it = 0; it < 4; ++it) {
    float4 xv = xr[it * 64 + lane];
    const float4* wr = (const float4*)Wg + (size_t)(it * 256 + lane * 4) * 2;
    float xs[4] = {xv.x, xv.y, xv.z, xv.w};
    union { unsigned short u[4]; uint2 v; } oo;
    oo.u[0] = f2bf(xv.x); oo.u[1] = f2bf(xv.y);
    oo.u[2] = f2bf(xv.z); oo.u[3] = f2bf(xv.w);
    *(uint2*)(xbr + it * 256 + lane * 4) = oo.v;
#pragma unroll
    for (int dd = 0; dd < 4; ++dd) {
      float4 wa = wr[dd * 2 + 0];
      float4 wb = wr[dd * 2 + 1];
      acc[0] += xs[dd] * wa.x; acc[1] += xs[dd] * wa.y;
      acc[2] += xs[dd] * wa.z; acc[3] += xs[dd] * wa.w;
      acc[4] += xs[dd] * wb.x; acc[5] += xs[dd] * wb.y;
      acc[6] += xs[dd] * wb.z; acc[7] += xs[dd] * wb.w;
    }
  }
#pragma unroll
  for (int e = 0; e < NUM_E; ++e)
#pragma unroll
    for (int off = 32; off > 0; off >>= 1)
      acc[e] += __shfl_down(acc[e], off);
  if (lane == 0) {
    float p[NUM_E];
    float mx = -1e30f;
#pragma unroll
    for (int e = 0; e < NUM_E; ++e) { p[e] = acc[e] + bg[e]; mx = fmaxf(mx, p[e]); }
    float ss = 0.f;
#pragma unroll
    for (int e = 0; e < NUM_E; ++e) { p[e] = expf(p[e] - mx); ss += p[e]; }
    float inv = 1.f / ss;
    int i0 = 0;
#pragma unroll
    for (int e = 1; e < NUM_E; ++e) if (p[e] > p[i0]) i0 = e;
    int i1 = (i0 == 0) ? 1 : 0;
#pragma unroll
    for (int e = 0; e < NUM_E; ++e) if (e != i0 && p[e] > p[i1]) i1 = e;
    tok_top[n] = i0 | (i1 << 8);
    tok_wts[n] = make_float2(p[i0] * inv, p[i1] * inv);
  }
}

// ---------------- gate2: per-expert compaction (R13-verified 256-thread) ----------------
__global__ __launch_bounds__(256) void gate2_kernel(const int* __restrict__ tok_top,
                                                    const float2* __restrict__ tok_wts,
                                                    int* __restrict__ counts,
                                                    int* __restrict__ tok_idx,
                                                    float* __restrict__ tok_w) {
  __shared__ int wsum[4];
  __shared__ int btot;
  const int e = blockIdx.x;
  const int t = threadIdx.x;
  const int lane = t & 63;
  const int wave = t >> 6;
  unsigned mask = 0;
  int cnt = 0;
#pragma unroll 8
  for (int j = 0; j < 32; ++j) {
    int top = tok_top[t * 32 + j];
    bool m = ((top & 0xff) == e) || (((top >> 8) & 0xff) == e);
    mask |= (unsigned)m << j;
    cnt += m;
  }
  int inc = cnt;
#pragma unroll
  for (int off = 1; off < 64; off <<= 1) {
    int v = __shfl_up(inc, off);
    if (lane >= off) inc += v;
  }
  if (lane == 63) wsum[wave] = inc;
  __syncthreads();
  if (t < 4) {
    int v = wsum[t];
    int ssum = v;
#pragma unroll
    for (int off = 1; off < 4; off <<= 1) {
      int u = __shfl_up(ssum, off);
      if (lane >= off) ssum += u;
    }
    wsum[t] = ssum - v;
    if (t == 3) btot = ssum;
  }
  __syncthreads();
  int slot = wsum[wave] + inc - cnt;
#pragma unroll 8
  for (int j = 0; j < 32; ++j) {
    if ((mask >> j) & 1u) {
      int n = t * 32 + j;
      int top = tok_top[n];
      float2 ww = tok_wts[n];
      bool m0 = (top & 0xff) == e;
      tok_idx[e * N_TOK + slot] = n;
      tok_w[e * N_TOK + slot] = m0 ? ww.x : ww.y;
      slot++;
    }
  }
  if (t == 0) counts[e] = btot;
}

// ---------------- FC1 GEMM + W2-transpose filler ----------------
// R14: 3264 blocks. bid%3==0 -> FC1 GEMM tile (1088 tiles, R8's verbatim
// 128x128/BK=64 loop + XCD mapping); else -> W2 transpose tile (2048 tiles,
// 128 no-ops). The transpose blocks BACKFILL the GEMM's tail round (the
// round-quantization mechanism: 1088 blocks at 4/CU = 1.06 rounds -> the 64
// tail blocks previously ran in a ~6%-occupancy second round costing +60us).
// XCD locality preserved: for bid%3==0, rank = bid/24 is the per-XCD ordinal
// (unique residue mod 24 per xcd) -> mt = xcd*17 + rank/8, nt = rank%8,
// identical tile->XCD grouping to R8 (FETCH 33MB).
__global__ __launch_bounds__(256, 4) void fc1_w2t_kernel(
    const unsigned short* __restrict__ A_src,  // x_bf16
    const unsigned short* __restrict__ wT,     // W1T
    const float* __restrict__ W2, unsigned short* __restrict__ W2T,
    const float* __restrict__ bias,            // b1
    const int* __restrict__ counts,
    const int* __restrict__ tok_idx,
    unsigned short* __restrict__ h_out)
{
  __shared__ __align__(16) unsigned char smem[33792];
  const int bid = blockIdx.x;
  const int role = bid % 3;
  if (role != 0) {
    const int wv = (bid / 3) * 2 + role - 1;   // 0..2175
    if (wv < 2048)
      wtile_transpose(W2 + (size_t)(wv >> 8) * (DIM * DIM),
                      W2T + (size_t)(wv >> 8) * (DIM * DIM),
                      (wv >> 4) & 15, wv & 15, (float(*)[65])smem);
    return;
  }
  const int xcd  = bid & 7;
  const int rank = bid / 24;                   // 0..135 within this xcd
  const int mt   = xcd * 17 + (rank >> 3);     // 0..135
  const int nt   = rank & 7;

  int e = -1, m0 = 0, base = 0;
  {
    int acc_tiles = 0, acc_rows = 0;
#pragma unroll
    for (int i = 0; i < NUM_E; ++i) {
      int c = counts[i];
      int t = (c + 127) >> 7;
      if (mt >= acc_tiles && mt < acc_tiles + t) {
        e = i; m0 = (mt - acc_tiles) * 128; base = acc_rows;
      }
      acc_tiles += t;
      acc_rows += t * 128;
    }
  }
  if (e < 0) return;
  const int count = counts[e];
  const int n0 = nt * 128;

  const int tid  = threadIdx.x;
  const int wave = tid >> 6;
  const int lane = tid & 63;
  const int l15  = lane & 15;
  const int quad = lane >> 4;
  const int wm   = wave & 1;
  const int wn   = wave >> 1;

  unsigned short* sA = (unsigned short*)smem;            // 2*4096 shorts
  unsigned short* sB = (unsigned short*)(smem + 16384);  // 2*4096 shorts

  const int r0 = 32 * wave + l15;
  const int r1 = r0 + 16;
  int s0 = m0 + r0; s0 = s0 < count ? s0 : count - 1;
  int s1 = m0 + r1; s1 = s1 < count ? s1 : count - 1;
  const size_t aOff0 = (size_t)tok_idx[e * N_TOK + s0] * DIM;
  const size_t aOff1 = (size_t)tok_idx[e * N_TOK + s1] * DIM;
  const unsigned short* wte = wT + (size_t)e * DIM * DIM;
  const size_t bOff0 = (size_t)(n0 + r0) * DIM;
  const size_t bOff1 = (size_t)(n0 + r1) * DIM;
  const int kl = quad * 8;
  const int c0 = (2 * wave + 0) * 512;
  const int c1 = (2 * wave + 1) * 512;

  const f32x4 vzero = {0.f, 0.f, 0.f, 0.f};
  f32x4 acc[4][4];
#pragma unroll
  for (int i = 0; i < 4; ++i)
#pragma unroll
    for (int j = 0; j < 4; ++j) acc[i][j] = vzero;

  for (int k0 = 0; k0 < DIM; k0 += 64) {
    async16(A_src + aOff0 + k0 + kl,      &sA[c0]);
    async16(A_src + aOff1 + k0 + kl,      &sA[c1]);
    async16(A_src + aOff0 + k0 + 32 + kl, &sA[4096 + c0]);
    async16(A_src + aOff1 + k0 + 32 + kl, &sA[4096 + c1]);
    async16(wte + bOff0 + k0 + kl,        &sB[c0]);
    async16(wte + bOff1 + k0 + kl,        &sB[c1]);
    async16(wte + bOff0 + k0 + 32 + kl,   &sB[4096 + c0]);
    async16(wte + bOff1 + k0 + 32 + kl,   &sB[4096 + c1]);
    __syncthreads();
#pragma unroll
    for (int s = 0; s < 2; ++s) {
      short8 af[4], bfr[4];
#pragma unroll
      for (int i = 0; i < 4; ++i)
        af[i] = *(const short8*)&sA[s * 4096 + (wm * 4 + i) * 512 + lane * 8];
#pragma unroll
      for (int j = 0; j < 4; ++j)
        bfr[j] = *(const short8*)&sB[s * 4096 + (wn * 4 + j) * 512 + lane * 8];
#pragma unroll
      for (int i = 0; i < 4; ++i)
#pragma unroll
        for (int j = 0; j < 4; ++j)
          acc[i][j] = __builtin_amdgcn_mfma_f32_16x16x32_bf16(af[i], bfr[j], acc[i][j], 0, 0, 0);
    }
    __syncthreads();
  }

  float bv[4];
#pragma unroll
  for (int j = 0; j < 4; ++j)
    bv[j] = bias[e * DIM + n0 + (wn * 4 + j) * 16 + l15];

  // C/D layout (m89-verified): col = lane&15, row = quad*4 + reg
#pragma unroll
  for (int i = 0; i < 4; ++i) {
    const int rbase = (wm * 4 + i) * 16 + quad * 4;
#pragma unroll
    for (int r = 0; r < 4; ++r) {
      const int slot = m0 + rbase + r;
      if (slot < count) {
        unsigned short* hp = h_out + (size_t)(base + slot) * DIM + n0;
#pragma unroll
        for (int j = 0; j < 4; ++j) {
          float v = acc[i][j][r] + bv[j];
          v = v > 0.f ? v : 0.f;
          hp[(wn * 4 + j) * 16 + l15] = f2bf(v);
        }
      }
    }
  }
}

// ---------------- FC2: 64x128 tiles, 6 blocks/CU ----------------
// Tail-shrink: per-block time ~halves and slots rise 1024->1536, so the
// round-quantization waste drops from +60us to <=+35us. LDS 24KB (no s_tok:
// epilogue reads tok_idx/tok_w direct from L2, R11-style). Same proven
// chunk layout / single-buffer loop; wave = 2 m-frags x 4 n-frags.
__global__ __launch_bounds__(256) void fc2_kernel(
    const unsigned short* __restrict__ A_src,  // h (compacted)
    const unsigned short* __restrict__ wT,     // W2T
    const float* __restrict__ bias,            // b2
    const int* __restrict__ counts,
    const int* __restrict__ tok_idx,
    const float* __restrict__ tok_w,
    float* __restrict__ out)
{
  const int bid = blockIdx.x;                  // 0..2111
  const int xcd = bid & 7;
  const int mt  = xcd * 33 + (bid >> 6);       // 0..263 (64-row m-tiles)
  const int nt  = (bid >> 3) & 7;

  // tile table: m-tiles of 64 rows; h base uses FC1's 128-padding
  int e = -1, m0 = 0, base = 0;
  {
    int at = 0, ar = 0;
#pragma unroll
    for (int i = 0; i < NUM_E; ++i) {
      int c = counts[i];
      int t = (c + 63) >> 6;
      if (mt >= at && mt < at + t) { e = i; m0 = (mt - at) * 64; base = ar; }
      at += t;
      ar += ((c + 127) >> 7) * 128;
    }
  }
  if (e < 0) return;
  const int count = counts[e];
  const int n0 = nt * 128;

  const int tid  = threadIdx.x;
  const int wave = tid >> 6;
  const int lane = tid & 63;
  const int l15  = lane & 15;
  const int quad = lane >> 4;
  const int wm   = wave & 1;      // m half (32 rows each)
  const int wn   = wave >> 1;     // n half (64 cols each)

  __shared__ unsigned short sA[4096];   // [plane2][chunk4][512]
  __shared__ unsigned short sB[8192];   // [plane2][chunk8][512]

  // staging: wave stages A chunk=wave (rows 16w+l15), B chunks 2w,2w+1
  const size_t aOff  = (size_t)(base + m0 + 16 * wave + l15) * DIM + quad * 8;
  const unsigned short* wte = wT + (size_t)e * DIM * DIM;
  const size_t bOff0 = (size_t)(n0 + 32 * wave + l15) * DIM + quad * 8;
  const size_t bOff1 = bOff0 + 16 * DIM;
  const int cA  = wave * 512;
  const int cB0 = 2 * wave * 512;
  const int cB1 = cB0 + 512;

  const f32x4 vzero = {0.f, 0.f, 0.f, 0.f};
  f32x4 acc[2][4];
#pragma unroll
  for (int i = 0; i < 2; ++i)
#pragma unroll
    for (int j = 0; j < 4; ++j) acc[i][j] = vzero;

  for (int k0 = 0; k0 < DIM; k0 += 64) {
    async16(A_src + aOff + k0,       &sA[cA]);
    async16(A_src + aOff + k0 + 32,  &sA[2048 + cA]);
    async16(wte + bOff0 + k0,        &sB[cB0]);
    async16(wte + bOff1 + k0,        &sB[cB1]);
    async16(wte + bOff0 + k0 + 32,   &sB[4096 + cB0]);
    async16(wte + bOff1 + k0 + 32,   &sB[4096 + cB1]);
    __syncthreads();
#pragma unroll
    for (int s = 0; s < 2; ++s) {
      short8 af[2], bfr[4];
#pragma unroll
      for (int i = 0; i < 2; ++i)
        af[i] = *(const short8*)&sA[s * 2048 + (wm * 2 + i) * 512 + lane * 8];
#pragma unroll
      for (int j = 0; j < 4; ++j)
        bfr[j] = *(const short8*)&sB[s * 4096 + (wn * 4 + j) * 512 + lane * 8];
#pragma unroll
      for (int i = 0; i < 2; ++i)
#pragma unroll
        for (int j = 0; j < 4; ++j)
          acc[i][j] = __builtin_amdgcn_mfma_f32_16x16x32_bf16(af[i], bfr[j], acc[i][j], 0, 0, 0);
    }
    __syncthreads();
  }

  float bv[4];
#pragma unroll
  for (int j = 0; j < 4; ++j)
    bv[j] = bias[e * DIM + n0 + (wn * 4 + j) * 16 + l15];

  // C/D layout: col = lane&15, row = quad*4 + reg
#pragma unroll
  for (int i = 0; i < 2; ++i) {
    const int rbase = (wm * 2 + i) * 16 + quad * 4;
#pragma unroll
    for (int r = 0; r < 4; ++r) {
      const int slot = m0 + rbase + r;
      if (slot < count) {
        const int tok = tok_idx[e * N_TOK + slot];
        const float wgt = tok_w[e * N_TOK + slot];
        float* op = out + (size_t)tok * DIM + n0;
#pragma unroll
        for (int j = 0; j < 4; ++j) {
          float v = acc[i][j][r] + bv[j];
          atomicAdd(&op[(wn * 4 + j) * 16 + l15], wgt * v);
        }
      }
    }
  }
}

// ---------------- launch ----------------
// R14 pipeline (4 dispatches):
//   1. prep_gate_w1 (4096): gate+x->bf16+zero(out) interleaved with W1T
//   2. gate2 (8)
//   3. fc1_w2t (3264): FC1 GEMM (1088, bid%3==0) + W2T filler (2048)
//   4. fc2 (2112): 64x128 tiles at 6/CU
// ws layout (bytes):
//   0        counts[8]
//   1024     tok_idx [8][8192] int    (256 KB)
//   263168   tok_w   [8][8192] float  (256 KB)
//   525312   x_bf16  [8192][1024]     (16 MB)
//   +16MB    W1T bf16 [8][1024][1024] (16 MB)
//   +32MB    W2T bf16                 (16 MB)
//   +48MB    h bf16, 17408 rows x1024 (34 MB)
//   +~82.5MB tok_top int[8192] (32KB), tok_wts float2[8192] (64KB)

extern "C" void kernel_launch(void* const* d_in, const int* in_sizes, int n_in,
                              void* d_out, int out_size, void* d_ws, size_t ws_size,
                              hipStream_t stream) {
  const float* x  = (const float*)d_in[0];
  const float* W1 = (const float*)d_in[1];
  const float* b1 = (const float*)d_in[2];
  const float* W2 = (const float*)d_in[3];
  const float* b2 = (const float*)d_in[4];
  const float* Wg = (const float*)d_in[5];
  const float* bg = (const float*)d_in[6];
  float* out = (float*)d_out;

  char* ws = (char*)d_ws;
  int*            counts  = (int*)(ws);
  int*            tok_idx = (int*)(ws + 1024);
  float*          tok_w   = (float*)(ws + 263168);
  unsigned short* xb      = (unsigned short*)(ws + 525312);
  unsigned short* w1t     = (unsigned short*)(ws + 525312 + 16777216ull);
  unsigned short* w2t     = (unsigned short*)(ws + 525312 + 2ull * 16777216ull);
  unsigned short* hb      = (unsigned short*)(ws + 525312 + 3ull * 16777216ull);
  size_t gate_off = 525312 + 3ull * 16777216ull + 35651584ull;
  int*            tok_top = (int*)(ws + gate_off);
  float2*         tok_wts = (float2*)(ws + gate_off + 32768);

  prep_gate_w1_kernel<<<4096, 256, 0, stream>>>(x, Wg, bg, tok_top, tok_wts, xb,
                                                out, W1, w1t);
  gate2_kernel<<<8, 256, 0, stream>>>(tok_top, tok_wts, counts, tok_idx, tok_w);
  fc1_w2t_kernel<<<3264, 256, 0, stream>>>(xb, w1t, W2, w2t, b1,
                                           counts, tok_idx, hb);
  fc2_kernel<<<2112, 256, 0, stream>>>(hb, w2t, b2, counts, tok_idx, tok_w, out);
}

// Round 11
// 384.639 us; speedup vs baseline: 1.0911x; 1.0911x over previous
//
#include <hip/hip_runtime.h>

#define NUM_E 8
#define N_TOK 8192
#define DIM 1024

typedef __attribute__((ext_vector_type(8))) short short8;
typedef __attribute__((ext_vector_type(4))) float f32x4;

// fp32 -> bf16 round-to-nearest-even
__device__ __forceinline__ unsigned short f2bf(float f) {
  unsigned int u = __float_as_uint(f);
  u = (u + 0x7fffu + ((u >> 16) & 1u)) >> 16;
  return (unsigned short)u;
}

// async global->LDS, 16B per lane. Global addr is per-lane; LDS dest is
// wave-uniform base + lane*16 (m104/m108 semantics).
__device__ __forceinline__ void async16(const unsigned short* g, unsigned short* l) {
  __builtin_amdgcn_global_load_lds((const __attribute__((address_space(1))) void*)g,
                                   (__attribute__((address_space(3))) void*)l,
                                   16, 0, 0);
}

// 64x64 W-transpose tile body (proven since R0): src fp32 [k][n] -> dst bf16 [n][k]
__device__ __forceinline__ void wtile_transpose(const float* src, unsigned short* dst,
                                                int tk, int tn, float (*s)[65]) {
  const int k0 = tk * 64, n0 = tn * 64;
  const int t = threadIdx.x;
  {
    const int rr = t >> 4;
    const int c4 = (t & 15) * 4;
#pragma unroll
    for (int i = 0; i < 4; ++i) {
      const int k = i * 16 + rr;
      float4 v = *(const float4*)&src[(size_t)(k0 + k) * DIM + n0 + c4];
      s[c4 + 0][k] = v.x; s[c4 + 1][k] = v.y;
      s[c4 + 2][k] = v.z; s[c4 + 3][k] = v.w;
    }
  }
  __syncthreads();
  {
    const int kq = (t & 7) * 8;
    const int nn = t >> 3;
#pragma unroll
    for (int r = 0; r < 2; ++r) {
      const int n = r * 32 + nn;
      union { unsigned short us[8]; uint4 v; } o;
#pragma unroll
      for (int j = 0; j < 8; ++j) o.us[j] = f2bf(s[n][kq + j]);
      *(uint4*)(dst + (size_t)(n0 + n) * DIM + k0 + kq) = o.v;
    }
  }
}

// ---------------- prep_gate: gating + x->bf16 + zero(out) ----------------
// R13-verified verbatim. 2048 blocks, 4 tokens/block.
__global__ __launch_bounds__(256) void prep_gate_kernel(
    const float* __restrict__ x, const float* __restrict__ Wg,
    const float* __restrict__ bg, int* __restrict__ tok_top,
    float2* __restrict__ tok_wts, unsigned short* __restrict__ xb,
    float* __restrict__ out) {
  {
    float4* oz = (float4*)(out + (size_t)blockIdx.x * 4096);
    const float4 z4 = {0.f, 0.f, 0.f, 0.f};
#pragma unroll
    for (int i = 0; i < 4; ++i) oz[i * 256 + threadIdx.x] = z4;
  }
  const int wave = threadIdx.x >> 6;
  const int lane = threadIdx.x & 63;
  const int n = blockIdx.x * 4 + wave;
  const float4* xr = (const float4*)(x + (size_t)n * DIM);
  unsigned short* xbr = xb + (size_t)n * DIM;
  float acc[NUM_E];
#pragma unroll
  for (int e = 0; e < NUM_E; ++e) acc[e] = 0.f;
#pragma unroll
  for (int it = 0; it < 4; ++it) {
    float4 xv = xr[it * 64 + lane];
    const float4* wr = (const float4*)Wg + (size_t)(it * 256 + lane * 4) * 2;
    float xs[4] = {xv.x, xv.y, xv.z, xv.w};
    union { unsigned short u[4]; uint2 v; } oo;
    oo.u[0] = f2bf(xv.x); oo.u[1] = f2bf(xv.y);
    oo.u[2] = f2bf(xv.z); oo.u[3] = f2bf(xv.w);
    *(uint2*)(xbr + it * 256 + lane * 4) = oo.v;
#pragma unroll
    for (int dd = 0; dd < 4; ++dd) {
      float4 wa = wr[dd * 2 + 0];
      float4 wb = wr[dd * 2 + 1];
      acc[0] += xs[dd] * wa.x; acc[1] += xs[dd] * wa.y;
      acc[2] += xs[dd] * wa.z; acc[3] += xs[dd] * wa.w;
      acc[4] += xs[dd] * wb.x; acc[5] += xs[dd] * wb.y;
      acc[6] += xs[dd] * wb.z; acc[7] += xs[dd] * wb.w;
    }
  }
#pragma unroll
  for (int e = 0; e < NUM_E; ++e)
#pragma unroll
    for (int off = 32; off > 0; off >>= 1)
      acc[e] += __shfl_down(acc[e], off);
  if (lane == 0) {
    float p[NUM_E];
    float mx = -1e30f;
#pragma unroll
    for (int e = 0; e < NUM_E; ++e) { p[e] = acc[e] + bg[e]; mx = fmaxf(mx, p[e]); }
    float ss = 0.f;
#pragma unroll
    for (int e = 0; e < NUM_E; ++e) { p[e] = expf(p[e] - mx); ss += p[e]; }
    float inv = 1.f / ss;
    int i0 = 0;
#pragma unroll
    for (int e = 1; e < NUM_E; ++e) if (p[e] > p[i0]) i0 = e;
    int i1 = (i0 == 0) ? 1 : 0;
#pragma unroll
    for (int e = 0; e < NUM_E; ++e) if (e != i0 && p[e] > p[i1]) i1 = e;
    tok_top[n] = i0 | (i1 << 8);
    tok_wts[n] = make_float2(p[i0] * inv, p[i1] * inv);
  }
}

// ---------------- prep_w1 + gate2 ----------------
// blocks [0,2048): W1 transpose tiles (W2 now rides inside fc1_w2t -- R14's
// free-filler discovery). blocks [2048,2056): gate2 compaction (R13-verified
// 256-thread body). No even/odd interleave (R14's regression suspect).
__global__ __launch_bounds__(256) void prep_w1_gate2_kernel(
    const float* __restrict__ W1, unsigned short* __restrict__ W1T,
    const int* __restrict__ tok_top, const float2* __restrict__ tok_wts,
    int* __restrict__ counts, int* __restrict__ tok_idx,
    float* __restrict__ tok_w) {
  __shared__ float s[64][65];
  __shared__ int wsum[4];
  __shared__ int btot;
  const int bid = blockIdx.x;
  if (bid < 2048) {
    wtile_transpose(W1 + (size_t)(bid >> 8) * (DIM * DIM),
                    W1T + (size_t)(bid >> 8) * (DIM * DIM),
                    (bid >> 4) & 15, bid & 15, s);
    return;
  }
  const int e = bid - 2048;
  const int t = threadIdx.x;
  const int lane = t & 63;
  const int wave = t >> 6;
  unsigned mask = 0;
  int cnt = 0;
#pragma unroll 8
  for (int j = 0; j < 32; ++j) {
    int top = tok_top[t * 32 + j];
    bool m = ((top & 0xff) == e) || (((top >> 8) & 0xff) == e);
    mask |= (unsigned)m << j;
    cnt += m;
  }
  int inc = cnt;
#pragma unroll
  for (int off = 1; off < 64; off <<= 1) {
    int v = __shfl_up(inc, off);
    if (lane >= off) inc += v;
  }
  if (lane == 63) wsum[wave] = inc;
  __syncthreads();
  if (t < 4) {
    int v = wsum[t];
    int ssum = v;
#pragma unroll
    for (int off = 1; off < 4; off <<= 1) {
      int u = __shfl_up(ssum, off);
      if (lane >= off) ssum += u;
    }
    wsum[t] = ssum - v;
    if (t == 3) btot = ssum;
  }
  __syncthreads();
  int slot = wsum[wave] + inc - cnt;
#pragma unroll 8
  for (int j = 0; j < 32; ++j) {
    if ((mask >> j) & 1u) {
      int n = t * 32 + j;
      int top = tok_top[n];
      float2 ww = tok_wts[n];
      bool m0 = (top & 0xff) == e;
      tok_idx[e * N_TOK + slot] = n;
      tok_w[e * N_TOK + slot] = m0 ? ww.x : ww.y;
      slot++;
    }
  }
  if (t == 0) counts[e] = btot;
}

// ---------------- FC1 GEMM + W2-transpose filler (R14-verified) ----------------
// 3264 blocks: bid%3==0 -> FC1 GEMM tile (1088, R8's verbatim loop + XCD
// mapping via rank=bid/24); else -> W2 transpose tile (2048 + 128 no-ops).
// R14 measured: the filler rides for free (fc1_w2t < fc1-alone's 119).
__global__ __launch_bounds__(256, 4) void fc1_w2t_kernel(
    const unsigned short* __restrict__ A_src,  // x_bf16
    const unsigned short* __restrict__ wT,     // W1T
    const float* __restrict__ W2, unsigned short* __restrict__ W2T,
    const float* __restrict__ bias,            // b1
    const int* __restrict__ counts,
    const int* __restrict__ tok_idx,
    unsigned short* __restrict__ h_out)
{
  __shared__ __align__(16) unsigned char smem[33792];
  const int bid = blockIdx.x;
  const int role = bid % 3;
  if (role != 0) {
    const int wv = (bid / 3) * 2 + role - 1;   // 0..2175
    if (wv < 2048)
      wtile_transpose(W2 + (size_t)(wv >> 8) * (DIM * DIM),
                      W2T + (size_t)(wv >> 8) * (DIM * DIM),
                      (wv >> 4) & 15, wv & 15, (float(*)[65])smem);
    return;
  }
  const int xcd  = bid & 7;
  const int rank = bid / 24;                   // 0..135 within this xcd
  const int mt   = xcd * 17 + (rank >> 3);
  const int nt   = rank & 7;

  int e = -1, m0 = 0, base = 0;
  {
    int acc_tiles = 0, acc_rows = 0;
#pragma unroll
    for (int i = 0; i < NUM_E; ++i) {
      int c = counts[i];
      int t = (c + 127) >> 7;
      if (mt >= acc_tiles && mt < acc_tiles + t) {
        e = i; m0 = (mt - acc_tiles) * 128; base = acc_rows;
      }
      acc_tiles += t;
      acc_rows += t * 128;
    }
  }
  if (e < 0) return;
  const int count = counts[e];
  const int n0 = nt * 128;

  const int tid  = threadIdx.x;
  const int wave = tid >> 6;
  const int lane = tid & 63;
  const int l15  = lane & 15;
  const int quad = lane >> 4;
  const int wm   = wave & 1;
  const int wn   = wave >> 1;

  unsigned short* sA = (unsigned short*)smem;            // 2*4096 shorts
  unsigned short* sB = (unsigned short*)(smem + 16384);  // 2*4096 shorts

  const int r0 = 32 * wave + l15;
  const int r1 = r0 + 16;
  int s0 = m0 + r0; s0 = s0 < count ? s0 : count - 1;
  int s1 = m0 + r1; s1 = s1 < count ? s1 : count - 1;
  const size_t aOff0 = (size_t)tok_idx[e * N_TOK + s0] * DIM;
  const size_t aOff1 = (size_t)tok_idx[e * N_TOK + s1] * DIM;
  const unsigned short* wte = wT + (size_t)e * DIM * DIM;
  const size_t bOff0 = (size_t)(n0 + r0) * DIM;
  const size_t bOff1 = (size_t)(n0 + r1) * DIM;
  const int kl = quad * 8;
  const int c0 = (2 * wave + 0) * 512;
  const int c1 = (2 * wave + 1) * 512;

  const f32x4 vzero = {0.f, 0.f, 0.f, 0.f};
  f32x4 acc[4][4];
#pragma unroll
  for (int i = 0; i < 4; ++i)
#pragma unroll
    for (int j = 0; j < 4; ++j) acc[i][j] = vzero;

  for (int k0 = 0; k0 < DIM; k0 += 64) {
    async16(A_src + aOff0 + k0 + kl,      &sA[c0]);
    async16(A_src + aOff1 + k0 + kl,      &sA[c1]);
    async16(A_src + aOff0 + k0 + 32 + kl, &sA[4096 + c0]);
    async16(A_src + aOff1 + k0 + 32 + kl, &sA[4096 + c1]);
    async16(wte + bOff0 + k0 + kl,        &sB[c0]);
    async16(wte + bOff1 + k0 + kl,        &sB[c1]);
    async16(wte + bOff0 + k0 + 32 + kl,   &sB[4096 + c0]);
    async16(wte + bOff1 + k0 + 32 + kl,   &sB[4096 + c1]);
    __syncthreads();
#pragma unroll
    for (int s = 0; s < 2; ++s) {
      short8 af[4], bfr[4];
#pragma unroll
      for (int i = 0; i < 4; ++i)
        af[i] = *(const short8*)&sA[s * 4096 + (wm * 4 + i) * 512 + lane * 8];
#pragma unroll
      for (int j = 0; j < 4; ++j)
        bfr[j] = *(const short8*)&sB[s * 4096 + (wn * 4 + j) * 512 + lane * 8];
#pragma unroll
      for (int i = 0; i < 4; ++i)
#pragma unroll
        for (int j = 0; j < 4; ++j)
          acc[i][j] = __builtin_amdgcn_mfma_f32_16x16x32_bf16(af[i], bfr[j], acc[i][j], 0, 0, 0);
    }
    __syncthreads();
  }

  float bv[4];
#pragma unroll
  for (int j = 0; j < 4; ++j)
    bv[j] = bias[e * DIM + n0 + (wn * 4 + j) * 16 + l15];

  // C/D layout (m89-verified): col = lane&15, row = quad*4 + reg
#pragma unroll
  for (int i = 0; i < 4; ++i) {
    const int rbase = (wm * 4 + i) * 16 + quad * 4;
#pragma unroll
    for (int r = 0; r < 4; ++r) {
      const int slot = m0 + rbase + r;
      if (slot < count) {
        unsigned short* hp = h_out + (size_t)(base + slot) * DIM + n0;
#pragma unroll
        for (int j = 0; j < 4; ++j) {
          float v = acc[i][j][r] + bv[j];
          v = v > 0.f ? v : 0.f;
          hp[(wn * 4 + j) * 16 + l15] = f2bf(v);
        }
      }
    }
  }
}

// ---------------- FC2: R13-verified 128x128 (XCD-mapped, s_tok epilogue) ----------------
__global__ __launch_bounds__(256, 4) void fc2_kernel(
    const unsigned short* __restrict__ A_src,  // h (compacted)
    const unsigned short* __restrict__ wT,     // W2T
    const float* __restrict__ bias,            // b2
    const int* __restrict__ counts,
    const int* __restrict__ tok_idx,
    const float* __restrict__ tok_w,
    float* __restrict__ out)
{
  const int bid = blockIdx.x;
  const int xcd = bid & 7;
  const int mt  = xcd * 17 + (bid >> 6);
  const int nt  = (bid >> 3) & 7;

  int e = -1, m0 = 0, base = 0;
  {
    int acc_tiles = 0, acc_rows = 0;
#pragma unroll
    for (int i = 0; i < NUM_E; ++i) {
      int c = counts[i];
      int t = (c + 127) >> 7;
      if (mt >= acc_tiles && mt < acc_tiles + t) {
        e = i; m0 = (mt - acc_tiles) * 128; base = acc_rows;
      }
      acc_tiles += t;
      acc_rows += t * 128;
    }
  }
  if (e < 0) return;
  const int count = counts[e];
  const int n0 = nt * 128;

  const int tid  = threadIdx.x;
  const int wave = tid >> 6;
  const int lane = tid & 63;
  const int l15  = lane & 15;
  const int quad = lane >> 4;
  const int wm   = wave & 1;
  const int wn   = wave >> 1;

  __shared__ unsigned short sA[2 * 4096];
  __shared__ unsigned short sB[2 * 4096];
  __shared__ int   s_tok[128];
  __shared__ float s_w[128];

  if (tid < 128) {
    int slot = m0 + tid;
    int cs = slot < count ? slot : count - 1;
    s_tok[tid] = tok_idx[e * N_TOK + cs];
    s_w[tid]   = slot < count ? tok_w[e * N_TOK + slot] : 0.f;
  }

  const int r0 = 32 * wave + l15;
  const int r1 = r0 + 16;
  const size_t aOff0 = (size_t)(base + m0 + r0) * DIM;
  const size_t aOff1 = (size_t)(base + m0 + r1) * DIM;
  const unsigned short* wte = wT + (size_t)e * DIM * DIM;
  const size_t bOff0 = (size_t)(n0 + r0) * DIM;
  const size_t bOff1 = (size_t)(n0 + r1) * DIM;
  const int kl = quad * 8;
  const int c0 = (2 * wave + 0) * 512;
  const int c1 = (2 * wave + 1) * 512;

  const f32x4 vzero = {0.f, 0.f, 0.f, 0.f};
  f32x4 acc[4][4];
#pragma unroll
  for (int i = 0; i < 4; ++i)
#pragma unroll
    for (int j = 0; j < 4; ++j) acc[i][j] = vzero;

  for (int k0 = 0; k0 < DIM; k0 += 64) {
    async16(A_src + aOff0 + k0 + kl,      &sA[c0]);
    async16(A_src + aOff1 + k0 + kl,      &sA[c1]);
    async16(A_src + aOff0 + k0 + 32 + kl, &sA[4096 + c0]);
    async16(A_src + aOff1 + k0 + 32 + kl, &sA[4096 + c1]);
    async16(wte + bOff0 + k0 + kl,        &sB[c0]);
    async16(wte + bOff1 + k0 + kl,        &sB[c1]);
    async16(wte + bOff0 + k0 + 32 + kl,   &sB[4096 + c0]);
    async16(wte + bOff1 + k0 + 32 + kl,   &sB[4096 + c1]);
    __syncthreads();
#pragma unroll
    for (int s = 0; s < 2; ++s) {
      short8 af[4], bfr[4];
#pragma unroll
      for (int i = 0; i < 4; ++i)
        af[i] = *(const short8*)&sA[s * 4096 + (wm * 4 + i) * 512 + lane * 8];
#pragma unroll
      for (int j = 0; j < 4; ++j)
        bfr[j] = *(const short8*)&sB[s * 4096 + (wn * 4 + j) * 512 + lane * 8];
#pragma unroll
      for (int i = 0; i < 4; ++i)
#pragma unroll
        for (int j = 0; j < 4; ++j)
          acc[i][j] = __builtin_amdgcn_mfma_f32_16x16x32_bf16(af[i], bfr[j], acc[i][j], 0, 0, 0);
    }
    __syncthreads();
  }

  float bv[4];
#pragma unroll
  for (int j = 0; j < 4; ++j)
    bv[j] = bias[e * DIM + n0 + (wn * 4 + j) * 16 + l15];

  // C/D layout (m89-verified): col = lane&15, row = quad*4 + reg
#pragma unroll
  for (int i = 0; i < 4; ++i) {
    const int rbase = (wm * 4 + i) * 16 + quad * 4;
#pragma unroll
    for (int r = 0; r < 4; ++r) {
      const int slot = m0 + rbase + r;
      if (slot < count) {
        const int rl = rbase + r;
        const int tok = s_tok[rl];
        const float w = s_w[rl];
        float* op = out + (size_t)tok * DIM + n0;
#pragma unroll
        for (int j = 0; j < 4; ++j) {
          float v = acc[i][j][r] + bv[j];
          atomicAdd(&op[(wn * 4 + j) * 16 + l15], w * v);
        }
      }
    }
  }
}

// ---------------- launch ----------------
// R15 pipeline (4 dispatches) -- consolidation:
//   1. prep_gate (2048): gate + x->bf16 + zero(out)          [R13-verified]
//   2. prep_w1_gate2 (2056): W1T only + gate2 riders          [half R13 prep_w]
//   3. fc1_w2t (3264): FC1 GEMM + W2T filler                  [R14-verified free]
//   4. fc2 (1088): 128x128                                     [R13-verified]
// ws layout (bytes):
//   0        counts[8]
//   1024     tok_idx [8][8192] int    (256 KB)
//   263168   tok_w   [8][8192] float  (256 KB)
//   525312   x_bf16  [8192][1024]     (16 MB)
//   +16MB    W1T bf16 [8][1024][1024] (16 MB)
//   +32MB    W2T bf16                 (16 MB)
//   +48MB    h bf16, 17408 rows x1024 (34 MB)
//   +~82.5MB tok_top int[8192] (32KB), tok_wts float2[8192] (64KB)

extern "C" void kernel_launch(void* const* d_in, const int* in_sizes, int n_in,
                              void* d_out, int out_size, void* d_ws, size_t ws_size,
                              hipStream_t stream) {
  const float* x  = (const float*)d_in[0];
  const float* W1 = (const float*)d_in[1];
  const float* b1 = (const float*)d_in[2];
  const float* W2 = (const float*)d_in[3];
  const float* b2 = (const float*)d_in[4];
  const float* Wg = (const float*)d_in[5];
  const float* bg = (const float*)d_in[6];
  float* out = (float*)d_out;

  char* ws = (char*)d_ws;
  int*            counts  = (int*)(ws);
  int*            tok_idx = (int*)(ws + 1024);
  float*          tok_w   = (float*)(ws + 263168);
  unsigned short* xb      = (unsigned short*)(ws + 525312);
  unsigned short* w1t     = (unsigned short*)(ws + 525312 + 16777216ull);
  unsigned short* w2t     = (unsigned short*)(ws + 525312 + 2ull * 16777216ull);
  unsigned short* hb      = (unsigned short*)(ws + 525312 + 3ull * 16777216ull);
  size_t gate_off = 525312 + 3ull * 16777216ull + 35651584ull;
  int*            tok_top = (int*)(ws + gate_off);
  float2*         tok_wts = (float2*)(ws + gate_off + 32768);

  prep_gate_kernel<<<2048, 256, 0, stream>>>(x, Wg, bg, tok_top, tok_wts, xb, out);
  prep_w1_gate2_kernel<<<2056, 256, 0, stream>>>(W1, w1t, tok_top, tok_wts,
                                                 counts, tok_idx, tok_w);
  fc1_w2t_kernel<<<3264, 256, 0, stream>>>(xb, w1t, W2, w2t, b1,
                                           counts, tok_idx, hb);
  fc2_kernel<<<1088, 256, 0, stream>>>(hb, w2t, b2, counts, tok_idx, tok_w, out);
}